// Round 4
// baseline (1321.907 us; speedup 1.0000x reference)
//
#include <hip/hip_runtime.h>

#define MAXNB 2048
#define ACC_STRIDE 516    // 512 + 4 floats: row base 4 banks apart

typedef __attribute__((ext_vector_type(8))) short short8;
typedef __attribute__((ext_vector_type(4))) float f32x4;

__global__ __launch_bounds__(512) void hist_kernel(
    const int* __restrict__ dst, int* __restrict__ hist, int n_edges)
{
    __shared__ int lh[MAXNB];
    const int t = threadIdx.x;
    for (int i = t; i < MAXNB; i += 512) lh[i] = 0;
    __syncthreads();
    for (int e = blockIdx.x * 512 + t; e < n_edges; e += gridDim.x * 512)
        atomicAdd(&lh[dst[e] >> 6], 1);
    __syncthreads();
    for (int i = t; i < MAXNB; i += 512) {
        int c = lh[i];
        if (c) atomicAdd(&hist[i], c);
    }
}

__global__ __launch_bounds__(64) void scan_kernel(
    const int* __restrict__ hist, int* __restrict__ bstart, int nb)
{
    const int lane = threadIdx.x;
    int running = 0;
    for (int base = 0; base < nb; base += 64) {
        int i = base + lane;
        int o = (i < nb) ? hist[i] : 0;
        int v = o;
#pragma unroll
        for (int off = 1; off < 64; off <<= 1) {
            int u = __shfl_up(v, off);
            if (lane >= off) v += u;
        }
        if (i < nb) bstart[i] = running + v - o;  // exclusive
        running += __shfl(v, 63);
    }
}

__global__ __launch_bounds__(512) void scatter_kernel(
    const int* __restrict__ src, const int* __restrict__ dst,
    const int* __restrict__ et, const int* __restrict__ bstart,
    int* __restrict__ cursor, unsigned int* __restrict__ recs,
    int n_edges, int chunk)
{
    __shared__ int lh[MAXNB];
    __shared__ int lbase[MAXNB];
    const int t = threadIdx.x;
    const int e0 = blockIdx.x * chunk;
    const int e1 = min(n_edges, e0 + chunk);
    for (int i = t; i < MAXNB; i += 512) lh[i] = 0;
    __syncthreads();
    for (int e = e0 + t; e < e1; e += 512) atomicAdd(&lh[dst[e] >> 6], 1);
    __syncthreads();
    for (int i = t; i < MAXNB; i += 512) {
        int c = lh[i];
        lbase[i] = c ? atomicAdd(&cursor[i], c) : 0;
        lh[i] = 0;
    }
    __syncthreads();
    for (int e = e0 + t; e < e1; e += 512) {
        int d = dst[e];
        int bkt = d >> 6;
        int rank = atomicAdd(&lh[bkt], 1);
        int pos = bstart[bkt] + lbase[bkt] + rank;
        recs[pos] = (unsigned)src[e] | ((unsigned)et[e] << 17)
                  | ((unsigned)(d & 63) << 20);
    }
}

// One-time: convert [root; W] into bf16 hi/lo, laid out exactly as the LDS
// image the bucket kernel wants: chunk c (0=root, 1..8=rel), hi block then lo
// block, each [j][k] with k-stride 72 shorts (144 B, 16B-aligned rows).
__global__ __launch_bounds__(256) void wprep_kernel(
    const float* __restrict__ W, const float* __restrict__ root,
    short* __restrict__ wb, int dout)
{
    int idx = blockIdx.x * 256 + threadIdx.x;
    int total = 9 * 64 * dout;
    if (idx >= total) return;
    int c = idx / (64 * dout);
    int rme = idx % (64 * dout);
    int kk = rme / dout;
    int j = rme % dout;
    float f = (c == 0) ? root[kk * dout + j]
                       : W[(size_t)(c - 1) * 64 * dout + kk * dout + j];
    unsigned u = __float_as_uint(f);
    short hi = (short)(u >> 16);
    float fl = f - __uint_as_float(u & 0xFFFF0000u);
    short lo = (short)(__float_as_uint(fl) >> 16);
    size_t cb = (size_t)c * dout * 144;
    wb[cb + (size_t)j * 72 + kk] = hi;
    wb[cb + (size_t)dout * 72 + (size_t)j * 72 + kk] = lo;
}

// One block (1024 threads = 16 waves) per bucket of 64 dst nodes.
// Phase 1: wave-per-edge LDS fp32 aggregation (lane = feature, conflict-free).
// Phase 2: MFMA bf16 hi/lo GEMM: out = [x | means] @ [root; W] + b.
template <int DOUT, int RELU>
__global__ __launch_bounds__(1024) void rgcn_bucket_kernel(
    const float* __restrict__ xin,       // (N, 64)
    const unsigned int* __restrict__ recs,
    const int* __restrict__ bstart,
    const int* __restrict__ hist,
    const short* __restrict__ wb,        // precomputed hi/lo chunks
    const float* __restrict__ bias,      // (DOUT)
    float* __restrict__ out,             // (N, DOUT)
    int n_nodes)
{
    constexpr int CHUNK16 = DOUT * 18;            // uint4s per chunk (hi+lo)
    constexpr int NPREF = (CHUNK16 + 1023) / 1024;
    __shared__ __align__(16) float acc_s[64 * ACC_STRIDE];  // 132096 B
    __shared__ uint4 wt4[CHUNK16];                          // 18432/9216 B
    __shared__ int   cnt_s[512];
    __shared__ float scale_s[512];
    short* wt_s = (short*)wt4;

    const int t = threadIdx.x;
    const int w = t >> 6;
    const int lane = t & 63;
    const int node0 = blockIdx.x * 64;
    const uint4* wbase = (const uint4*)wb;

    // prefetch W chunk 0 (root) into registers; consumed after phase 1
    uint4 wreg[NPREF];
#pragma unroll
    for (int i = 0; i < NPREF; ++i) {
        int idx = t + i * 1024;
        if (idx < CHUNK16) wreg[i] = wbase[idx];
    }

    // zero accumulators
    {
        float4 z{0.f, 0.f, 0.f, 0.f};
        float4* a4 = (float4*)acc_s;
        for (int i = t; i < (64 * ACC_STRIDE) / 4; i += 1024) a4[i] = z;
        if (t < 512) cnt_s[t] = 0;
    }
    __syncthreads();

    // ---- phase 1: one wave per edge, 8-edge batches ----
    const int start = bstart[blockIdx.x];
    const int len = hist[blockIdx.x];
    for (int base = w * 8; base < len; base += 128) {
        const int nb2 = min(8, len - base);
        unsigned myrec = 0;
        if (lane < nb2) myrec = recs[start + base + lane];
        unsigned r[8];
        float v[8];
#pragma unroll
        for (int k = 0; k < 8; ++k) {
            if (k < nb2) {
                r[k] = __shfl(myrec, k);
                v[k] = xin[(size_t)(r[k] & 0x1FFFF) * 64 + lane];
            }
        }
#pragma unroll
        for (int k = 0; k < 8; ++k) {
            if (k < nb2) {
                const int dl = (r[k] >> 20) & 63;
                const int rel = (r[k] >> 17) & 7;
                atomicAdd(&acc_s[dl * ACC_STRIDE + rel * 64 + lane], v[k]);
            }
        }
        if (lane < nb2)
            atomicAdd(&cnt_s[((myrec >> 20) & 63) * 8 + ((myrec >> 17) & 7)], 1);
    }
    __syncthreads();
    if (t < 512) scale_s[t] = 1.0f / fmaxf((float)cnt_s[t], 1.0f);

    // ---- phase 2: 9 chunks of K=64 (root, then 8 relations) ----
    constexpr int NTILES = 4 * (DOUT / 16);  // 16 or 8 active waves
    const int quad = lane >> 4;
    const int l16 = lane & 15;
    const int mt = w & 3;
    const int nt = w >> 2;
    const int m = mt * 16 + l16;   // A row (node within bucket)
    const int j = nt * 16 + l16;   // B col (output feature)
    f32x4 d = {0.f, 0.f, 0.f, 0.f};

    for (int c = 0; c < 9; ++c) {
        // commit prefetched chunk c to LDS (pure uint4 copy, conflict-free)
#pragma unroll
        for (int i = 0; i < NPREF; ++i) {
            int idx = t + i * 1024;
            if (idx < CHUNK16) wt4[idx] = wreg[i];
        }
        __syncthreads();
        // prefetch chunk c+1
        if (c + 1 < 9) {
            const uint4* src = wbase + (size_t)(c + 1) * CHUNK16;
#pragma unroll
            for (int i = 0; i < NPREF; ++i) {
                int idx = t + i * 1024;
                if (idx < CHUNK16) wreg[i] = src[idx];
            }
        }
        // compute chunk c
        if (w < NTILES) {
            const float sc = (c > 0) ? scale_s[m * 8 + (c - 1)] : 1.0f;
#pragma unroll
            for (int ks = 0; ks < 2; ++ks) {
                const int ko = ks * 32 + quad * 8;
                short8 bh = *(const short8*)&wt_s[(size_t)j * 72 + ko];
                short8 bl = *(const short8*)&wt_s[(size_t)DOUT * 72 + (size_t)j * 72 + ko];
                float a[8];
                if (c == 0) {
                    const int node = node0 + m;
                    if (node < n_nodes) {
                        const float* xr = xin + (size_t)node * 64 + ko;
#pragma unroll
                        for (int i2 = 0; i2 < 8; ++i2) a[i2] = xr[i2];
                    } else {
#pragma unroll
                        for (int i2 = 0; i2 < 8; ++i2) a[i2] = 0.0f;
                    }
                } else {
                    const float* ar = &acc_s[m * ACC_STRIDE + (c - 1) * 64 + ko];
#pragma unroll
                    for (int i2 = 0; i2 < 8; ++i2) a[i2] = ar[i2] * sc;
                }
                short8 ah, al;
#pragma unroll
                for (int i2 = 0; i2 < 8; ++i2) {
                    float av = a[i2];
                    unsigned u = __float_as_uint(av);
                    ah[i2] = (short)(u >> 16);
                    float fl = av - __uint_as_float(u & 0xFFFF0000u);
                    al[i2] = (short)(__float_as_uint(fl) >> 16);
                }
                d = __builtin_amdgcn_mfma_f32_16x16x32_bf16(ah, bh, d, 0, 0, 0);
                d = __builtin_amdgcn_mfma_f32_16x16x32_bf16(ah, bl, d, 0, 0, 0);
                d = __builtin_amdgcn_mfma_f32_16x16x32_bf16(al, bh, d, 0, 0, 0);
            }
        }
        __syncthreads();
    }

    // ---- epilogue: C/D layout col=lane&15 (=j), row=quad*4+reg (=m) ----
    if (w < NTILES) {
        const float bj = bias[j];
#pragma unroll
        for (int r = 0; r < 4; ++r) {
            const int mm = mt * 16 + quad * 4 + r;
            const int node = node0 + mm;
            if (node < n_nodes) {
                float v = d[r] + bj;
                if (RELU) v = fmaxf(v, 0.0f);
                out[(size_t)node * DOUT + j] = v;
            }
        }
    }
}

extern "C" void kernel_launch(void* const* d_in, const int* in_sizes, int n_in,
                              void* d_out, int out_size, void* d_ws, size_t ws_size,
                              hipStream_t stream) {
    const float* x     = (const float*)d_in[0];
    const float* W1    = (const float*)d_in[1];
    const float* root1 = (const float*)d_in[2];
    const float* b1    = (const float*)d_in[3];
    const float* W2    = (const float*)d_in[4];
    const float* root2 = (const float*)d_in[5];
    const float* b2    = (const float*)d_in[6];
    const int*   src   = (const int*)d_in[7];
    const int*   dst   = (const int*)d_in[8];
    const int*   et    = (const int*)d_in[9];

    const int N = in_sizes[0] / 64;
    const int E = in_sizes[7];
    const int NB = (N + 63) / 64;  // 1563 for N=100000; must be <= MAXNB

    // ws layout (u32 units): recs(E) | hist(NB) | bstart(NB) | cursor(NB) |
    //   pad | wb1 (9*64*144 shorts) | wb2 (9*32*144 shorts) | pad | h (N*64 f32)
    unsigned int* recs = (unsigned int*)d_ws;
    int* hist = (int*)(recs + E);
    int* bstart = hist + NB;
    int* cursor = bstart + NB;
    size_t off = (size_t)E + 3 * (size_t)NB;
    off = (off + 3) & ~(size_t)3;
    short* wb1 = (short*)((unsigned int*)d_ws + off);
    off += (9 * 64 * 144) / 2;
    short* wb2 = (short*)((unsigned int*)d_ws + off);
    off += (9 * 32 * 144) / 2;
    off = (off + 3) & ~(size_t)3;
    float* h = (float*)d_ws + off;

    hipMemsetAsync(hist, 0, (size_t)3 * NB * sizeof(int), stream);
    wprep_kernel<<<(9 * 64 * 64 + 255) / 256, 256, 0, stream>>>(W1, root1, wb1, 64);
    wprep_kernel<<<(9 * 64 * 32 + 255) / 256, 256, 0, stream>>>(W2, root2, wb2, 32);
    hist_kernel<<<192, 512, 0, stream>>>(dst, hist, E);
    scan_kernel<<<1, 64, 0, stream>>>(hist, bstart, NB);
    const int chunk = (E + 191) / 192;
    scatter_kernel<<<192, 512, 0, stream>>>(src, dst, et, bstart, cursor, recs, E, chunk);

    rgcn_bucket_kernel<64, 1><<<NB, 1024, 0, stream>>>(
        x, recs, bstart, hist, wb1, b1, h, N);
    rgcn_bucket_kernel<32, 0><<<NB, 1024, 0, stream>>>(
        h, recs, bstart, hist, wb2, b2, (float*)d_out, N);
}

// Round 5
// 558.287 us; speedup vs baseline: 2.3678x; 2.3678x over previous
//
#include <hip/hip_runtime.h>

typedef __attribute__((ext_vector_type(8))) short short8;
typedef __attribute__((ext_vector_type(4))) float f32x4;

__device__ __forceinline__ unsigned short f2bf(float f) {
    unsigned u = __float_as_uint(f);
    u += 0x7FFF + ((u >> 16) & 1);   // round-to-nearest-even
    return (unsigned short)(u >> 16);
}
__device__ __forceinline__ float bf2f(unsigned short h) {
    return __uint_as_float(((unsigned)h) << 16);
}

// ---------- preprocessing: counting sort by key = dst*8 + rel ----------

__global__ __launch_bounds__(256) void hist8_kernel(
    const int* __restrict__ dst, const int* __restrict__ et,
    int* __restrict__ hist, int E)
{
    int e = blockIdx.x * 256 + threadIdx.x;
    if (e < E) atomicAdd(&hist[dst[e] * 8 + et[e]], 1);
}

#define SCAN_TILE 4096
__global__ __launch_bounds__(1024) void scanA_kernel(
    const int* __restrict__ hist, int* __restrict__ bstart,
    int* __restrict__ partial, int nkeys)
{
    __shared__ int wsum[16];
    const int t = threadIdx.x;
    const int lane = t & 63, w = t >> 6;
    const int base = blockIdx.x * SCAN_TILE + t * 4;
    int v[4];
    int s = 0;
#pragma unroll
    for (int i = 0; i < 4; ++i) {
        v[i] = (base + i < nkeys) ? hist[base + i] : 0;
        s += v[i];
    }
    int inc = s;
#pragma unroll
    for (int off = 1; off < 64; off <<= 1) {
        int u = __shfl_up(inc, off);
        if (lane >= off) inc += u;
    }
    if (lane == 63) wsum[w] = inc;
    __syncthreads();
    if (w == 0 && lane < 16) {
        int ws = wsum[lane];
        int winc = ws;
#pragma unroll
        for (int off = 1; off < 16; off <<= 1) {
            int u = __shfl_up(winc, off);
            if (lane >= off) winc += u;
        }
        wsum[lane] = winc - ws;   // exclusive (lockstep within wave 0)
    }
    __syncthreads();
    int run = wsum[w] + (inc - s);
    int tbase = run;
#pragma unroll
    for (int i = 0; i < 4; ++i) {
        if (base + i < nkeys) bstart[base + i] = run;
        run += v[i];
    }
    if (t == 1023) partial[blockIdx.x] = tbase + s;   // block total
}

__global__ __launch_bounds__(64) void scanB_kernel(
    const int* __restrict__ partial, int* __restrict__ pscan,
    int* __restrict__ bstart_end, int nblk)
{
    const int lane = threadIdx.x;
    int running = 0;
    for (int b = 0; b < nblk; b += 64) {
        int i = b + lane;
        int o = (i < nblk) ? partial[i] : 0;
        int v = o;
#pragma unroll
        for (int off = 1; off < 64; off <<= 1) {
            int u = __shfl_up(v, off);
            if (lane >= off) v += u;
        }
        if (i < nblk) pscan[i] = running + v - o;
        running += __shfl(v, 63);
    }
    if (lane == 0) *bstart_end = running;   // == E
}

__global__ __launch_bounds__(1024) void scanC_kernel(
    int* __restrict__ bstart, const int* __restrict__ pscan, int nkeys)
{
    int i = blockIdx.x * 1024 + threadIdx.x;
    if (i < nkeys) bstart[i] += pscan[i / SCAN_TILE];
}

__global__ __launch_bounds__(256) void scatter8_kernel(
    const int* __restrict__ src, const int* __restrict__ dst,
    const int* __restrict__ et, const int* __restrict__ bstart,
    int* __restrict__ cursor, unsigned* __restrict__ srt, int E)
{
    int e = blockIdx.x * 256 + threadIdx.x;
    if (e < E) {
        int key = dst[e] * 8 + et[e];
        int pos = bstart[key] + atomicAdd(&cursor[key], 1);
        srt[pos] = (unsigned)src[e] | ((unsigned)et[e] << 17);
    }
}

// ---------- W preconversion: [c]( hi[j][72] | lo[j][72] ) per 64-K chunk ----------

__global__ __launch_bounds__(256) void wprep_kernel(
    const float* __restrict__ W, const float* __restrict__ root,
    short* __restrict__ wb, int dout)
{
    int idx = blockIdx.x * 256 + threadIdx.x;
    int total = 9 * 64 * dout;
    if (idx >= total) return;
    int c = idx / (64 * dout);
    int rme = idx % (64 * dout);
    int kk = rme / dout;
    int j = rme % dout;
    float f = (c == 0) ? root[kk * dout + j]
                       : W[(size_t)(c - 1) * 64 * dout + kk * dout + j];
    unsigned u = __float_as_uint(f);
    short hi = (short)(u >> 16);
    float fl = f - __uint_as_float(u & 0xFFFF0000u);
    short lo = (short)(__float_as_uint(fl) >> 16);
    size_t cb = (size_t)c * dout * 144;
    wb[cb + (size_t)j * 72 + kk] = hi;
    wb[cb + (size_t)dout * 72 + (size_t)j * 72 + kk] = lo;
}

// ---------- aggregation: one wave per node, lane = feature dim ----------
// Writes A[n] = [ x_bf16 (LAYER1 only) | mean_0 .. mean_7 ] (bf16, 576 cols).

template <int LAYER1>
__global__ __launch_bounds__(512) void agg_kernel(
    const float* __restrict__ x,              // layer1 input (N,64) fp32
    const unsigned short* __restrict__ Ain,   // layer2: bf16 h rows = A cols 0..63
    const unsigned* __restrict__ srt,         // sorted (src | rel<<17)
    const int* __restrict__ bstart,           // (N*8 + 1)
    unsigned short* __restrict__ A,           // (N, 576) bf16
    int n_nodes)
{
    const int t = threadIdx.x;
    const int lane = t & 63;
    const int node = blockIdx.x * 8 + (t >> 6);
    if (node >= n_nodes) return;
    const int kb = node * 8;
    int myb = 0;
    if (lane < 9) myb = bstart[kb + lane];
    const int e0 = __shfl(myb, 0);
    const int e1 = __shfl(myb, 8);

    float acc[8];
#pragma unroll
    for (int j = 0; j < 8; ++j) acc[j] = 0.0f;

#define LDX(q) (LAYER1 ? x[(size_t)((q) & 0x1FFFF) * 64 + lane] \
                       : bf2f(Ain[(size_t)((q) & 0x1FFFF) * 576 + lane]))
#define ACCSEL(q, v) { int r_ = (int)((q) >> 17);                      \
        _Pragma("unroll") for (int j_ = 0; j_ < 8; ++j_)               \
            acc[j_] += (r_ == j_) ? (v) : 0.0f; }

    for (int base = e0; base < e1; base += 64) {
        const int blen = min(64, e1 - base);
        unsigned rec = 0;
        if (lane < blen) rec = srt[base + lane];
        int k = 0;
        for (; k + 4 <= blen; k += 4) {
            unsigned q0 = __shfl(rec, k), q1 = __shfl(rec, k + 1);
            unsigned q2 = __shfl(rec, k + 2), q3 = __shfl(rec, k + 3);
            float v0 = LDX(q0), v1 = LDX(q1), v2 = LDX(q2), v3 = LDX(q3);
            ACCSEL(q0, v0); ACCSEL(q1, v1); ACCSEL(q2, v2); ACCSEL(q3, v3);
        }
        for (; k < blen; ++k) {
            unsigned q = __shfl(rec, k);
            float v = LDX(q);
            ACCSEL(q, v);
        }
    }
#undef LDX
#undef ACCSEL

    unsigned short* arow = A + (size_t)node * 576;
    if (LAYER1) arow[lane] = f2bf(x[(size_t)node * 64 + lane]);
#pragma unroll
    for (int r = 0; r < 8; ++r) {
        int c0 = __shfl(myb, r);
        int c1 = __shfl(myb, r + 1);
        float m = acc[r] / fmaxf((float)(c1 - c0), 1.0f);
        arow[64 + r * 64 + lane] = f2bf(m);
    }
}

// ---------- dense: C = A @ [root; W] + b, MFMA bf16 (B in hi/lo) ----------
// Block = 64 nodes x DOUT cols, 512 threads = 8 waves.

template <int DOUT, int RELU, int OUTBF>
__global__ __launch_bounds__(512) void dense_kernel(
    const unsigned short* __restrict__ A,   // (N, 576) bf16
    const short* __restrict__ wb,           // preconverted hi/lo chunks
    const float* __restrict__ bias,
    float* __restrict__ outf,               // fp32 out (OUTBF=0)
    unsigned short* __restrict__ outb,      // bf16 out rows stride 576 (OUTBF=1)
    int n_nodes)
{
    constexpr int CHUNK16 = DOUT * 18;              // uint4s per chunk (hi+lo)
    constexpr int NLOOP = (CHUNK16 + 511) / 512;
    constexpr int JPW = DOUT / 32;                  // j-tiles per wave (2 or 1)
    __shared__ uint4 wt4[CHUNK16];
    short* wt_s = (short*)wt4;

    const int t = threadIdx.x;
    const int w = t >> 6, lane = t & 63;
    const int quad = lane >> 4, l16 = lane & 15;
    const int node0 = blockIdx.x * 64;
    const int mt = w & 3;        // 4 m-tiles of 16 nodes
    const int jg = w >> 2;       // 2 j-groups
    const int m = mt * 16 + l16;
    const int row = min(node0 + m, n_nodes - 1);
    const unsigned short* arow = A + (size_t)row * 576;
    const uint4* wb16 = (const uint4*)wb;

    f32x4 d[JPW];
#pragma unroll
    for (int i = 0; i < JPW; ++i) d[i] = {0.f, 0.f, 0.f, 0.f};

    uint4 wreg[NLOOP];
#pragma unroll
    for (int i = 0; i < NLOOP; ++i) {
        int idx = t + i * 512;
        if (idx < CHUNK16) wreg[i] = wb16[idx];
    }
    short8 a0 = *(const short8*)(arow + quad * 8);
    short8 a1 = *(const short8*)(arow + 32 + quad * 8);

    for (int c = 0; c < 9; ++c) {
#pragma unroll
        for (int i = 0; i < NLOOP; ++i) {
            int idx = t + i * 512;
            if (idx < CHUNK16) wt4[idx] = wreg[i];
        }
        __syncthreads();
        short8 ca0 = a0, ca1 = a1;
        if (c + 1 < 9) {
            const uint4* nx = wb16 + (size_t)(c + 1) * CHUNK16;
#pragma unroll
            for (int i = 0; i < NLOOP; ++i) {
                int idx = t + i * 512;
                if (idx < CHUNK16) wreg[i] = nx[idx];
            }
            a0 = *(const short8*)(arow + (c + 1) * 64 + quad * 8);
            a1 = *(const short8*)(arow + (c + 1) * 64 + 32 + quad * 8);
        }
#pragma unroll
        for (int jj = 0; jj < JPW; ++jj) {
            const int j = (jg * JPW + jj) * 16 + l16;
            short8 bh0 = *(const short8*)&wt_s[j * 72 + quad * 8];
            short8 bl0 = *(const short8*)&wt_s[DOUT * 72 + j * 72 + quad * 8];
            short8 bh1 = *(const short8*)&wt_s[j * 72 + 32 + quad * 8];
            short8 bl1 = *(const short8*)&wt_s[DOUT * 72 + j * 72 + 32 + quad * 8];
            d[jj] = __builtin_amdgcn_mfma_f32_16x16x32_bf16(ca0, bh0, d[jj], 0, 0, 0);
            d[jj] = __builtin_amdgcn_mfma_f32_16x16x32_bf16(ca0, bl0, d[jj], 0, 0, 0);
            d[jj] = __builtin_amdgcn_mfma_f32_16x16x32_bf16(ca1, bh1, d[jj], 0, 0, 0);
            d[jj] = __builtin_amdgcn_mfma_f32_16x16x32_bf16(ca1, bl1, d[jj], 0, 0, 0);
        }
        __syncthreads();
    }

    // epilogue: C/D layout col = lane&15 (j), row = quad*4 + reg (m)
#pragma unroll
    for (int jj = 0; jj < JPW; ++jj) {
        const int j = (jg * JPW + jj) * 16 + l16;
        const float bj = bias[j];
#pragma unroll
        for (int r = 0; r < 4; ++r) {
            const int mm = mt * 16 + quad * 4 + r;
            const int node = node0 + mm;
            if (node < n_nodes) {
                float v = d[jj][r] + bj;
                if (RELU) v = fmaxf(v, 0.0f);
                if (OUTBF) outb[(size_t)node * 576 + j] = f2bf(v);
                else       outf[(size_t)node * DOUT + j] = v;
            }
        }
    }
}

extern "C" void kernel_launch(void* const* d_in, const int* in_sizes, int n_in,
                              void* d_out, int out_size, void* d_ws, size_t ws_size,
                              hipStream_t stream) {
    const float* x     = (const float*)d_in[0];
    const float* W1    = (const float*)d_in[1];
    const float* root1 = (const float*)d_in[2];
    const float* b1    = (const float*)d_in[3];
    const float* W2    = (const float*)d_in[4];
    const float* root2 = (const float*)d_in[5];
    const float* b2    = (const float*)d_in[6];
    const int*   src   = (const int*)d_in[7];
    const int*   dst   = (const int*)d_in[8];
    const int*   et    = (const int*)d_in[9];

    const int N = in_sizes[0] / 64;
    const int E = in_sizes[7];
    const int KEYS = N * 8;

    char* p = (char*)d_ws;
    auto alloc = [&](size_t bytes) {
        char* r = p;
        p += (bytes + 15) & ~(size_t)15;
        return r;
    };
    unsigned* srt    = (unsigned*)alloc((size_t)E * 4);
    int* hist        = (int*)alloc((size_t)KEYS * 4);       // hist|cursor adjacent
    int* cursor      = (int*)alloc((size_t)KEYS * 4);
    int* bstart      = (int*)alloc((size_t)(KEYS + 1) * 4);
    int* partial     = (int*)alloc(256 * 4);
    int* pscan       = (int*)alloc(256 * 4);
    short* wb1       = (short*)alloc((size_t)9 * 64 * 144 * 2);
    short* wb2       = (short*)alloc((size_t)9 * 32 * 144 * 2);
    unsigned short* A = (unsigned short*)alloc((size_t)N * 576 * 2);
    (void)cursor;  // contiguity: memset covers hist+cursor together

    hipMemsetAsync(hist, 0, (size_t)KEYS * 8, stream);
    wprep_kernel<<<(9 * 64 * 64 + 255) / 256, 256, 0, stream>>>(W1, root1, wb1, 64);
    wprep_kernel<<<(9 * 64 * 32 + 255) / 256, 256, 0, stream>>>(W2, root2, wb2, 32);
    hist8_kernel<<<(E + 255) / 256, 256, 0, stream>>>(dst, et, hist, E);
    const int nscan = (KEYS + SCAN_TILE - 1) / SCAN_TILE;
    scanA_kernel<<<nscan, 1024, 0, stream>>>(hist, bstart, partial, KEYS);
    scanB_kernel<<<1, 64, 0, stream>>>(partial, pscan, bstart + KEYS, nscan);
    scanC_kernel<<<(KEYS + 1023) / 1024, 1024, 0, stream>>>(bstart, pscan, KEYS);
    scatter8_kernel<<<(E + 255) / 256, 256, 0, stream>>>(src, dst, et, bstart, cursor, srt, E);

    agg_kernel<1><<<(N + 7) / 8, 512, 0, stream>>>(x, nullptr, srt, bstart, A, N);
    dense_kernel<64, 1, 1><<<(N + 63) / 64, 512, 0, stream>>>(
        A, wb1, b1, nullptr, A, N);
    agg_kernel<0><<<(N + 7) / 8, 512, 0, stream>>>(nullptr, A, srt, bstart, A, N);
    dense_kernel<32, 0, 0><<<(N + 63) / 64, 512, 0, stream>>>(
        A, wb2, b2, (float*)d_out, nullptr, N);
}

// Round 6
// 466.358 us; speedup vs baseline: 2.8345x; 1.1971x over previous
//
#include <hip/hip_runtime.h>

typedef _Float16 half8 __attribute__((ext_vector_type(8)));
typedef __attribute__((ext_vector_type(4))) float f32x4;

__device__ __forceinline__ unsigned short f2h(float f) {
    _Float16 h = (_Float16)f;
    return *(unsigned short*)&h;
}
__device__ __forceinline__ float h2f(unsigned short u) {
    _Float16 h = *(_Float16*)&u;
    return (float)h;
}

// ---------- preprocessing: counting sort by key = dst*8 + rel ----------

__global__ __launch_bounds__(256) void hist8_kernel(
    const int* __restrict__ dst, const int* __restrict__ et,
    int* __restrict__ hist, int E)
{
    int e = blockIdx.x * 256 + threadIdx.x;
    if (e < E) atomicAdd(&hist[dst[e] * 8 + et[e]], 1);
}

#define SCAN_TILE 4096
__global__ __launch_bounds__(1024) void scanA_kernel(
    const int* __restrict__ hist, int* __restrict__ bstart,
    int* __restrict__ partial, int nkeys)
{
    __shared__ int wsum[16];
    const int t = threadIdx.x;
    const int lane = t & 63, w = t >> 6;
    const int base = blockIdx.x * SCAN_TILE + t * 4;
    int v[4];
    int s = 0;
#pragma unroll
    for (int i = 0; i < 4; ++i) {
        v[i] = (base + i < nkeys) ? hist[base + i] : 0;
        s += v[i];
    }
    int inc = s;
#pragma unroll
    for (int off = 1; off < 64; off <<= 1) {
        int u = __shfl_up(inc, off);
        if (lane >= off) inc += u;
    }
    if (lane == 63) wsum[w] = inc;
    __syncthreads();
    if (w == 0 && lane < 16) {
        int ws = wsum[lane];
        int winc = ws;
#pragma unroll
        for (int off = 1; off < 16; off <<= 1) {
            int u = __shfl_up(winc, off);
            if (lane >= off) winc += u;
        }
        wsum[lane] = winc - ws;   // exclusive
    }
    __syncthreads();
    int run = wsum[w] + (inc - s);
    int tbase = run;
#pragma unroll
    for (int i = 0; i < 4; ++i) {
        if (base + i < nkeys) bstart[base + i] = run;
        run += v[i];
    }
    if (t == 1023) partial[blockIdx.x] = tbase + s;   // block total
}

__global__ __launch_bounds__(64) void scanB_kernel(
    const int* __restrict__ partial, int* __restrict__ pscan,
    int* __restrict__ bstart_end, int nblk)
{
    const int lane = threadIdx.x;
    int running = 0;
    for (int b = 0; b < nblk; b += 64) {
        int i = b + lane;
        int o = (i < nblk) ? partial[i] : 0;
        int v = o;
#pragma unroll
        for (int off = 1; off < 64; off <<= 1) {
            int u = __shfl_up(v, off);
            if (lane >= off) v += u;
        }
        if (i < nblk) pscan[i] = running + v - o;
        running += __shfl(v, 63);
    }
    if (lane == 0) *bstart_end = running;   // == E
}

__global__ __launch_bounds__(1024) void scanC_kernel(
    int* __restrict__ bstart, const int* __restrict__ pscan, int nkeys)
{
    int i = blockIdx.x * 1024 + threadIdx.x;
    if (i < nkeys) bstart[i] += pscan[i / SCAN_TILE];
}

__global__ __launch_bounds__(256) void scatter8_kernel(
    const int* __restrict__ src, const int* __restrict__ dst,
    const int* __restrict__ et, const int* __restrict__ bstart,
    int* __restrict__ cursor, unsigned* __restrict__ srt, int E)
{
    int e = blockIdx.x * 256 + threadIdx.x;
    if (e < E) {
        int key = dst[e] * 8 + et[e];
        int pos = bstart[key] + atomicAdd(&cursor[key], 1);
        srt[pos] = (unsigned)src[e] | ((unsigned)et[e] << 17);
    }
}

// ---------- W preconversion: f16 image, chunk c: [j][k stride 72] ----------

__global__ __launch_bounds__(256) void wprep_kernel(
    const float* __restrict__ W, const float* __restrict__ root,
    unsigned short* __restrict__ wb, int dout)
{
    int idx = blockIdx.x * 256 + threadIdx.x;
    int total = 9 * 64 * dout;
    if (idx >= total) return;
    int c = idx / (64 * dout);
    int rme = idx % (64 * dout);
    int kk = rme / dout;
    int j = rme % dout;
    float f = (c == 0) ? root[kk * dout + j]
                       : W[(size_t)(c - 1) * 64 * dout + kk * dout + j];
    wb[(size_t)c * dout * 72 + (size_t)j * 72 + kk] = f2h(f);
}

// ---------- aggregation: one wave per node, lane = feature dim ----------
// Writes A[n] = [ x_f16 (LAYER1) | mean_0 .. mean_7 ] (f16, 576 cols).

template <int LAYER1>
__global__ __launch_bounds__(512) void agg_kernel(
    const float* __restrict__ x,              // layer1 input (N,64) fp32
    const unsigned short* __restrict__ Ain,   // layer2: f16 h rows = A cols 0..63
    const unsigned* __restrict__ srt,         // sorted (src | rel<<17)
    const int* __restrict__ bstart,           // (N*8 + 1)
    unsigned short* __restrict__ A,           // (N, 576) f16
    int n_nodes)
{
    const int t = threadIdx.x;
    const int lane = t & 63;
    const int node = blockIdx.x * 8 + (t >> 6);
    if (node >= n_nodes) return;
    const int kb = node * 8;
    int myb = 0;
    if (lane < 9) myb = bstart[kb + lane];
    const int e0 = __shfl(myb, 0);
    const int e1 = __shfl(myb, 8);

    float acc[8];
#pragma unroll
    for (int j = 0; j < 8; ++j) acc[j] = 0.0f;

#define LDX(q) (LAYER1 ? x[(size_t)((q) & 0x1FFFF) * 64 + lane] \
                       : h2f(Ain[(size_t)((q) & 0x1FFFF) * 576 + lane]))
#define ACCSEL(q, v) { int r_ = (int)((q) >> 17);                      \
        _Pragma("unroll") for (int j_ = 0; j_ < 8; ++j_)               \
            acc[j_] += (r_ == j_) ? (v) : 0.0f; }

    for (int base = e0; base < e1; base += 64) {
        const int blen = min(64, e1 - base);
        unsigned rec = 0;
        if (lane < blen) rec = srt[base + lane];
        int k = 0;
        for (; k + 4 <= blen; k += 4) {
            unsigned q0 = __shfl(rec, k), q1 = __shfl(rec, k + 1);
            unsigned q2 = __shfl(rec, k + 2), q3 = __shfl(rec, k + 3);
            float v0 = LDX(q0), v1 = LDX(q1), v2 = LDX(q2), v3 = LDX(q3);
            ACCSEL(q0, v0); ACCSEL(q1, v1); ACCSEL(q2, v2); ACCSEL(q3, v3);
        }
        for (; k < blen; ++k) {
            unsigned q = __shfl(rec, k);
            float v = LDX(q);
            ACCSEL(q, v);
        }
    }
#undef LDX
#undef ACCSEL

    unsigned short* arow = A + (size_t)node * 576;
    if (LAYER1) arow[lane] = f2h(x[(size_t)node * 64 + lane]);
#pragma unroll
    for (int r = 0; r < 8; ++r) {
        int c0 = __shfl(myb, r);
        int c1 = __shfl(myb, r + 1);
        float m = acc[r] / fmaxf((float)(c1 - c0), 1.0f);
        arow[64 + r * 64 + lane] = f2h(m);
    }
}

// ---------- dense: C = A @ [root; W] + b, f16 MFMA, whole W in LDS ----------
// Block = 128 nodes, 512 threads = 8 waves (wave = one 16-row m-tile, all j).

template <int DOUT, int RELU, int OUTH>
__global__ __launch_bounds__(512, 2) void dense_kernel(
    const unsigned short* __restrict__ A,   // (N, 576) f16
    const unsigned short* __restrict__ wb,  // (9, DOUT, 72) f16
    const float* __restrict__ bias,
    float* __restrict__ outf,               // fp32 out (OUTH=0)
    unsigned short* __restrict__ outh,      // f16 out rows stride 576 (OUTH=1)
    int n_nodes)
{
    constexpr int WSHORTS = 9 * DOUT * 72;  // 41472 (83KB) or 20736 (41KB)
    __shared__ __align__(16) unsigned short wt_s[WSHORTS];

    const int t = threadIdx.x;
    const int w = t >> 6, lane = t & 63;
    const int quad = lane >> 4, l16 = lane & 15;
    const int node0 = blockIdx.x * 128;
    const int m = w * 16 + l16;
    const int row = min(node0 + m, n_nodes - 1);
    const unsigned short* arow = A + (size_t)row * 576;

    // prefetch entire A row (9 chunks x 2 frags = 72 VGPRs)
    half8 a[18];
#pragma unroll
    for (int c = 0; c < 9; ++c) {
        a[2 * c]     = *(const half8*)(arow + c * 64 + quad * 8);
        a[2 * c + 1] = *(const half8*)(arow + c * 64 + 32 + quad * 8);
    }
    // stage entire W image
    {
        uint4* d4 = (uint4*)wt_s;
        const uint4* s4 = (const uint4*)wb;
        for (int i = t; i < WSHORTS / 8; i += 512) d4[i] = s4[i];
    }
    __syncthreads();

    constexpr int JPW = DOUT / 16;
    f32x4 d[JPW];
#pragma unroll
    for (int i = 0; i < JPW; ++i) d[i] = {0.f, 0.f, 0.f, 0.f};

#pragma unroll
    for (int c = 0; c < 9; ++c) {
#pragma unroll
        for (int jj = 0; jj < JPW; ++jj) {
            const int j = jj * 16 + l16;
            half8 b0 = *(const half8*)&wt_s[c * DOUT * 72 + j * 72 + quad * 8];
            half8 b1 = *(const half8*)&wt_s[c * DOUT * 72 + j * 72 + 32 + quad * 8];
            d[jj] = __builtin_amdgcn_mfma_f32_16x16x32_f16(a[2 * c], b0, d[jj], 0, 0, 0);
            d[jj] = __builtin_amdgcn_mfma_f32_16x16x32_f16(a[2 * c + 1], b1, d[jj], 0, 0, 0);
        }
    }

    // epilogue: C/D layout col = lane&15 (j), row = quad*4 + reg (m)
#pragma unroll
    for (int jj = 0; jj < JPW; ++jj) {
        const int j = jj * 16 + l16;
        const float bj = bias[j];
#pragma unroll
        for (int r = 0; r < 4; ++r) {
            const int node = node0 + w * 16 + quad * 4 + r;
            if (node < n_nodes) {
                float v = d[jj][r] + bj;
                if (RELU) v = fmaxf(v, 0.0f);
                if (OUTH) outh[(size_t)node * 576 + j] = f2h(v);
                else      outf[(size_t)node * DOUT + j] = v;
            }
        }
    }
}

extern "C" void kernel_launch(void* const* d_in, const int* in_sizes, int n_in,
                              void* d_out, int out_size, void* d_ws, size_t ws_size,
                              hipStream_t stream) {
    const float* x     = (const float*)d_in[0];
    const float* W1    = (const float*)d_in[1];
    const float* root1 = (const float*)d_in[2];
    const float* b1    = (const float*)d_in[3];
    const float* W2    = (const float*)d_in[4];
    const float* root2 = (const float*)d_in[5];
    const float* b2    = (const float*)d_in[6];
    const int*   src   = (const int*)d_in[7];
    const int*   dst   = (const int*)d_in[8];
    const int*   et    = (const int*)d_in[9];

    const int N = in_sizes[0] / 64;
    const int E = in_sizes[7];
    const int KEYS = N * 8;

    char* p = (char*)d_ws;
    auto alloc = [&](size_t bytes) {
        char* r = p;
        p += (bytes + 15) & ~(size_t)15;
        return r;
    };
    unsigned* srt      = (unsigned*)alloc((size_t)E * 4);
    int* hist          = (int*)alloc((size_t)KEYS * 4);   // hist|cursor adjacent
    int* cursor        = (int*)alloc((size_t)KEYS * 4);
    int* bstart        = (int*)alloc((size_t)(KEYS + 1) * 4);
    int* partial       = (int*)alloc(256 * 4);
    int* pscan         = (int*)alloc(256 * 4);
    unsigned short* wb1 = (unsigned short*)alloc((size_t)9 * 64 * 72 * 2);
    unsigned short* wb2 = (unsigned short*)alloc((size_t)9 * 32 * 72 * 2);
    unsigned short* A   = (unsigned short*)alloc((size_t)N * 576 * 2);
    (void)cursor;  // memset covers hist+cursor together (contiguous)

    hipMemsetAsync(hist, 0, (size_t)KEYS * 8, stream);
    wprep_kernel<<<(9 * 64 * 64 + 255) / 256, 256, 0, stream>>>(W1, root1, wb1, 64);
    wprep_kernel<<<(9 * 64 * 32 + 255) / 256, 256, 0, stream>>>(W2, root2, wb2, 32);
    hist8_kernel<<<(E + 255) / 256, 256, 0, stream>>>(dst, et, hist, E);
    const int nscan = (KEYS + SCAN_TILE - 1) / SCAN_TILE;
    scanA_kernel<<<nscan, 1024, 0, stream>>>(hist, bstart, partial, KEYS);
    scanB_kernel<<<1, 64, 0, stream>>>(partial, pscan, bstart + KEYS, nscan);
    scanC_kernel<<<(KEYS + 1023) / 1024, 1024, 0, stream>>>(bstart, pscan, KEYS);
    scatter8_kernel<<<(E + 255) / 256, 256, 0, stream>>>(src, dst, et, bstart, cursor, srt, E);

    agg_kernel<1><<<(N + 7) / 8, 512, 0, stream>>>(x, nullptr, srt, bstart, A, N);
    dense_kernel<64, 1, 1><<<(N + 127) / 128, 512, 0, stream>>>(
        A, wb1, b1, nullptr, A, N);
    agg_kernel<0><<<(N + 7) / 8, 512, 0, stream>>>(nullptr, A, srt, bstart, A, N);
    dense_kernel<32, 0, 0><<<(N + 127) / 128, 512, 0, stream>>>(
        A, wb2, b2, (float*)d_out, nullptr, N);
}